// Round 7
// baseline (368.063 us; speedup 1.0000x reference)
//
#include <hip/hip_runtime.h>

// Problem constants
#define H   16
#define E   300
#define D   768
#define HD  48
#define QL  64
#define KL  64
#define NH  64          // n(4) * h(16)
#define ROWS 384        // 256 Q rows + 64 K + 64 V
#define SPLITK 12
#define NCHUNK 16       // e-chunk partial count
#define NBLK 256        // cooperative grid size

// Workspace float offsets
#define OFF_PP 0                              // Ppart[12][384][768]
#define OFF_A  (SPLITK*ROWS*D)                // 3,538,944  A[nh][e][q]
#define OFF_B  (OFF_A + NH*E*QL)              // 4,767,744  B[nh][k][q]
#define OFF_SP (OFF_B + NH*KL*QL)             // 5,029,888  Sp[16][nh][q][k]
#define OFF_BAR 9224192                       // barrier counters (unsigned), end of data
// data end = 9,224,192 floats = 36.9 MB ; barrier region 256 B after that

// ---------------------------------------------------------------------------
// Fast device-scope grid barrier (generation counter).  bar[0] = arrivals,
// bar[32] = generation (128 B apart -> separate L2 lines).  __threadfence on
// both sides handles cross-XCD L2 writeback/invalidate (G16).
// ---------------------------------------------------------------------------
__device__ __forceinline__ void grid_barrier(unsigned* bar)
{
    __threadfence();                          // release this thread's writes
    __syncthreads();
    if (threadIdx.x == 0) {
        unsigned gen = __hip_atomic_load(bar + 32, __ATOMIC_RELAXED, __HIP_MEMORY_SCOPE_AGENT);
        unsigned prev = __hip_atomic_fetch_add(bar, 1u, __ATOMIC_ACQ_REL, __HIP_MEMORY_SCOPE_AGENT);
        if (prev + 1u == (unsigned)NBLK) {
            __hip_atomic_store(bar, 0u, __ATOMIC_RELAXED, __HIP_MEMORY_SCOPE_AGENT);
            __hip_atomic_fetch_add(bar + 32, 1u, __ATOMIC_RELEASE, __HIP_MEMORY_SCOPE_AGENT);
        } else {
            while (__hip_atomic_load(bar + 32, __ATOMIC_ACQUIRE, __HIP_MEMORY_SCOPE_AGENT) == gen)
                __builtin_amdgcn_s_sleep(2);
        }
    }
    __syncthreads();
    __threadfence();                          // acquire: invalidate stale lines
}

// ===========================================================================
// Cooperative fused kernel: P1 proj -> bar -> P3 ab(fold) -> bar -> P4 main
// -> bar -> P5 out(fold).  All bodies identical to the proven discrete ones.
// ===========================================================================
__global__ __launch_bounds__(256, 1) void fused_kernel(
    const float* __restrict__ qin, const float* __restrict__ kin, const float* __restrict__ vin,
    const float* __restrict__ Wq, const float* __restrict__ bq_,
    const float* __restrict__ Wk, const float* __restrict__ bk_,
    const float* __restrict__ Wv, const float* __restrict__ bv_,
    const float* __restrict__ memo, float* __restrict__ ws, float* __restrict__ outp)
{
    unsigned* bar = (unsigned*)(ws + OFF_BAR);

    __shared__ union SU {
        struct { float XsT[32][132]; float Ws2[2][32][128]; } p1;  // 49.7 KB
        struct { float QsT[48][68];  float RsT[48][132];    } p3;  // 38.4 KB
        struct { float As[75 * 64];  float Bs[64][68];      } p4;  // 36.6 KB
        struct { float S_l[16][65];  float V_l[64][52];     } p5;  // 17.5 KB
    } sm;

    const int bid = blockIdx.x;
    const int tid = threadIdx.x;

    // ===================== P1: QKV projection -> 12 splitK partials ==========
    if (bid < 216) {
        const int ks     = bid / 18;
        const int rc     = bid % 18;
        const int rowblk = rc / 6;
        const int col0   = (rc % 6) * 128;
        const int kbase  = ks * 64;
        const int g0     = rowblk * 128;
        const float* Wlo = (g0      < 256) ? Wq : Wk;
        const float* Whi = (g0 + 64 < 256) ? Wq : Wv;

        const int half = tid >> 7;            // wave-uniform
        const int loc  = tid & 127;
        const int r0a  = (loc >> 4) * 4;
        const int c0a  = (loc & 15) * 4;

        float acc[8][8];
        #pragma unroll
        for (int i = 0; i < 8; i++)
            #pragma unroll
            for (int j = 0; j < 8; j++) acc[i][j] = 0.f;

        for (int kk2 = 0; kk2 < 64; kk2 += 32) {
            #pragma unroll
            for (int it = 0; it < 4; it++) {  // stage X tile transposed
                const int idx = it * 256 + tid;
                const int row = idx >> 3;
                const int d4  = (idx & 7) * 4;
                const int grow = g0 + row;
                const float* src = (grow < 256) ? (qin + grow * D)
                                 : (grow < 320) ? (kin + (grow - 256) * D)
                                                : (vin + (grow - 320) * D);
                const float4 xv = *(const float4*)(src + kbase + kk2 + d4);
                sm.p1.XsT[d4 + 0][row] = xv.x; sm.p1.XsT[d4 + 1][row] = xv.y;
                sm.p1.XsT[d4 + 2][row] = xv.z; sm.p1.XsT[d4 + 3][row] = xv.w;
            }
            #pragma unroll
            for (int it = 0; it < 8; it++) {  // stage both W tiles
                const int idx = it * 256 + tid;
                const int s   = idx >> 10;
                const int rem = idx & 1023;
                const int dk  = rem >> 5;
                const int c4  = (rem & 31) * 4;
                *(float4*)&sm.p1.Ws2[s][dk][c4] =
                    *(const float4*)((s ? Whi : Wlo) + (kbase + kk2 + dk) * D + col0 + c4);
            }
            __syncthreads();
            #pragma unroll
            for (int dk = 0; dk < 32; dk++) {
                const float4 xa = *(const float4*)&sm.p1.XsT[dk][half * 64 + r0a];
                const float4 xb = *(const float4*)&sm.p1.XsT[dk][half * 64 + r0a + 32];
                const float4 wa = *(const float4*)&sm.p1.Ws2[half][dk][c0a];
                const float4 wb = *(const float4*)&sm.p1.Ws2[half][dk][c0a + 64];
                const float xr[8] = {xa.x, xa.y, xa.z, xa.w, xb.x, xb.y, xb.z, xb.w};
                const float wc[8] = {wa.x, wa.y, wa.z, wa.w, wb.x, wb.y, wb.z, wb.w};
                #pragma unroll
                for (int i = 0; i < 8; i++)
                    #pragma unroll
                    for (int j = 0; j < 8; j++)
                        acc[i][j] = fmaf(xr[i], wc[j], acc[i][j]);
            }
            __syncthreads();
        }
        float* P = ws + OFF_PP + ks * (ROWS * D);
        #pragma unroll
        for (int i = 0; i < 8; i++) {
            const int row = g0 + half * 64 + r0a + (i < 4 ? i : 28 + i);
            *(float4*)(P + row * D + col0 + c0a) =
                make_float4(acc[i][0], acc[i][1], acc[i][2], acc[i][3]);
            *(float4*)(P + row * D + col0 + c0a + 64) =
                make_float4(acc[i][4], acc[i][5], acc[i][6], acc[i][7]);
        }
    }
    grid_barrier(bar);

    // ===================== P3: A = mem.Q, B = K.Q (partials folded) ==========
    if (bid < 192) {
        const int nh = bid & 63;
        const int rg = bid >> 6;
        const int n = nh >> 4, h = nh & 15;
        const float* PP = ws + OFF_PP;
        float* A = ws + OFF_A;
        float* B = ws + OFF_B;

        for (int l = tid; l < 64 * 12; l += 256) {   // Q: reduce 12 + bias, transposed
            const int q  = l / 12;
            const int d4 = (l % 12) * 4;
            float4 s = make_float4(0.f, 0.f, 0.f, 0.f);
            #pragma unroll
            for (int c = 0; c < SPLITK; c++) {
                const float4 p = *(const float4*)(PP + c * (ROWS * D) + (n * QL + q) * D + h * HD + d4);
                s.x += p.x; s.y += p.y; s.z += p.z; s.w += p.w;
            }
            const float4 bb = *(const float4*)(bq_ + h * HD + d4);
            sm.p3.QsT[d4 + 0][q] = s.x + bb.x; sm.p3.QsT[d4 + 1][q] = s.y + bb.y;
            sm.p3.QsT[d4 + 2][q] = s.z + bb.z; sm.p3.QsT[d4 + 3][q] = s.w + bb.w;
        }
        for (int l = tid; l < 128 * 12; l += 256) {  // rows: memo or K(reduce+bias)
            const int row = l / 12;
            const int d4  = (l % 12) * 4;
            const int rr  = rg * 128 + row;
            float4 s = make_float4(0.f, 0.f, 0.f, 0.f);
            if (rr < E) {
                s = *(const float4*)(memo + rr * D + h * HD + d4);
            } else if (rr < E + KL) {
                #pragma unroll
                for (int c = 0; c < SPLITK; c++) {
                    const float4 p = *(const float4*)(PP + c * (ROWS * D) + (256 + rr - E) * D + h * HD + d4);
                    s.x += p.x; s.y += p.y; s.z += p.z; s.w += p.w;
                }
                const float4 bb = *(const float4*)(bk_ + h * HD + d4);
                s.x += bb.x; s.y += bb.y; s.z += bb.z; s.w += bb.w;
            }
            sm.p3.RsT[d4 + 0][row] = s.x; sm.p3.RsT[d4 + 1][row] = s.y;
            sm.p3.RsT[d4 + 2][row] = s.z; sm.p3.RsT[d4 + 3][row] = s.w;
        }
        __syncthreads();

        const int r0 = (tid >> 4) * 8;
        const int q0 = (tid & 15) * 4;
        float acc[8][4];
        #pragma unroll
        for (int i = 0; i < 8; i++)
            #pragma unroll
            for (int j = 0; j < 4; j++) acc[i][j] = 0.f;

        #pragma unroll 4
        for (int d = 0; d < HD; d++) {
            const float4 rf0 = *(const float4*)&sm.p3.RsT[d][r0];
            const float4 rf1 = *(const float4*)&sm.p3.RsT[d][r0 + 4];
            const float4 qf  = *(const float4*)&sm.p3.QsT[d][q0];
            const float rr8[8] = {rf0.x, rf0.y, rf0.z, rf0.w, rf1.x, rf1.y, rf1.z, rf1.w};
            #pragma unroll
            for (int i = 0; i < 8; i++) {
                acc[i][0] = fmaf(rr8[i], qf.x, acc[i][0]);
                acc[i][1] = fmaf(rr8[i], qf.y, acc[i][1]);
                acc[i][2] = fmaf(rr8[i], qf.z, acc[i][2]);
                acc[i][3] = fmaf(rr8[i], qf.w, acc[i][3]);
            }
        }
        #pragma unroll
        for (int i = 0; i < 8; i++) {
            const int rr = rg * 128 + r0 + i;
            const float4 av = make_float4(acc[i][0], acc[i][1], acc[i][2], acc[i][3]);
            if (rr < E)            *(float4*)(A + (nh * E + rr) * QL + q0) = av;
            else if (rr < E + KL)  *(float4*)(B + (nh * KL + (rr - E)) * QL + q0) = av;
        }
    }
    grid_barrier(bar);

    // ===================== P4: fused core ====================================
    {
        const int nh = bid & 63;
        const int cgI = bid >> 6;
        const int lane = tid & 63;
        const int w = tid >> 6;

        const float* Ag = ws + OFF_A + (nh * E + cgI * 75) * QL;
        for (int idx = tid; idx < 1200; idx += 256)
            *(float4*)&sm.p4.As[idx * 4] = *(const float4*)(Ag + idx * 4);
        const float* Bg = ws + OFF_B + nh * (KL * QL);
        #pragma unroll
        for (int it = 0; it < 4; it++) {
            const int idx = it * 256 + tid;
            const int k  = idx >> 4;
            const int q4 = (idx & 15) * 4;
            *(float4*)&sm.p4.Bs[k][q4] = *(const float4*)(Bg + idx * 4);
        }
        __syncthreads();

        float b[64];
        #pragma unroll
        for (int j = 0; j < 16; j++)
            *(float4*)&b[j * 4] = *(const float4*)&sm.p4.Bs[lane][j * 4];

        float s[64];
        #pragma unroll
        for (int j = 0; j < 64; j++) s[j] = 0.f;

        const int eBeg = w * 19;
        const int eEnd = (eBeg + 19 < 75) ? eBeg + 19 : 75;
        for (int e = eBeg; e < eEnd; e++) {
            float m[64];
            #pragma unroll
            for (int j4 = 0; j4 < 16; j4++) {
                const float4 a = *(const float4*)&sm.p4.As[e * 64 + j4 * 4];  // broadcast
                m[j4 * 4 + 0] = fmaxf(a.x + b[j4 * 4 + 0], 0.f);
                m[j4 * 4 + 1] = fmaxf(a.y + b[j4 * 4 + 1], 0.f);
                m[j4 * 4 + 2] = fmaxf(a.z + b[j4 * 4 + 2], 0.f);
                m[j4 * 4 + 3] = fmaxf(a.w + b[j4 * 4 + 3], 0.f);
            }
            float p0 = 0.f, p1 = 0.f, p2 = 0.f, p3 = 0.f;
            #pragma unroll
            for (int j4 = 0; j4 < 16; j4++) {
                p0 += m[j4 * 4 + 0]; p1 += m[j4 * 4 + 1];
                p2 += m[j4 * 4 + 2]; p3 += m[j4 * 4 + 3];
            }
            const float p = (p0 + p1) + (p2 + p3);
            #pragma unroll
            for (int j = 0; j < 64; j++)
                s[j] = fmaf(m[j], p, s[j]);
        }

        float* Sp = ws + OFF_SP + ((cgI * 4 + w) * NH + nh) * (QL * KL);
        #pragma unroll
        for (int q = 0; q < 64; q++)
            Sp[q * KL + lane] = s[q];
    }
    grid_barrier(bar);

    // ===================== P5: S-reduce + S.V epilogue (V folded) ============
    {
        const int nh = bid & 63;
        const int qq = bid >> 6;
        const int n = nh >> 4, h = nh & 15;
        const int q0 = qq * 16;
        const float* Sp = ws + OFF_SP;
        const float* PP = ws + OFF_PP;

        for (int l = tid; l < 64 * 12; l += 256) {   // V: reduce 12 + bias
            const int k  = l / 12;
            const int d4 = (l % 12) * 4;
            float4 s = make_float4(0.f, 0.f, 0.f, 0.f);
            #pragma unroll
            for (int c = 0; c < SPLITK; c++) {
                const float4 p = *(const float4*)(PP + c * (ROWS * D) + (320 + k) * D + h * HD + d4);
                s.x += p.x; s.y += p.y; s.z += p.z; s.w += p.w;
            }
            const float4 bb = *(const float4*)(bv_ + h * HD + d4);
            *(float4*)&sm.p5.V_l[k][d4] = make_float4(s.x + bb.x, s.y + bb.y, s.z + bb.z, s.w + bb.w);
        }
        #pragma unroll
        for (int it = 0; it < 4; it++) {             // sum 16 S-partials
            const int idx = it * 256 + tid;
            const int qi = idx >> 6, k = idx & 63;
            float sum = 0.f;
            #pragma unroll
            for (int c = 0; c < NCHUNK; c++)
                sum += Sp[((c * NH + nh) * QL + q0 + qi) * KL + k];
            sm.p5.S_l[qi][k] = sum;
        }
        __syncthreads();

        const int qi = tid >> 4;
        const int dg = tid & 15;                     // 12 active
        if (dg < 12) {
            float a0 = 0.f, a1 = 0.f, a2 = 0.f, a3 = 0.f;
            #pragma unroll 8
            for (int k = 0; k < KL; k++) {
                const float sv = sm.p5.S_l[qi][k];
                const float4 vf = *(const float4*)&sm.p5.V_l[k][dg * 4];
                a0 = fmaf(sv, vf.x, a0); a1 = fmaf(sv, vf.y, a1);
                a2 = fmaf(sv, vf.z, a2); a3 = fmaf(sv, vf.w, a3);
            }
            *(float4*)(outp + (n * QL + q0 + qi) * D + h * HD + dg * 4) =
                make_float4(a0, a1, a2, a3);
        }
    }
}

// ===========================================================================
// Discrete-path fallback kernels (R6-proven bodies)
// ===========================================================================
__global__ __launch_bounds__(256, 1) void proj_kernel(
    const float* __restrict__ qin, const float* __restrict__ kin, const float* __restrict__ vin,
    const float* __restrict__ Wq, const float* __restrict__ Wk, const float* __restrict__ Wv,
    float* __restrict__ ws)
{
    const int rowblk = blockIdx.x;
    const int col0   = blockIdx.y * 128;
    const int ks     = blockIdx.z;
    const int kbase  = ks * 64;
    const int g0     = rowblk * 128;
    const float* Wlo = (g0      < 256) ? Wq : Wk;
    const float* Whi = (g0 + 64 < 256) ? Wq : Wv;

    __shared__ float XsT[32][132];
    __shared__ float Ws2[2][32][128];

    const int tid  = threadIdx.x;
    const int half = tid >> 7;
    const int loc  = tid & 127;
    const int r0a  = (loc >> 4) * 4;
    const int c0a  = (loc & 15) * 4;

    float acc[8][8];
    #pragma unroll
    for (int i = 0; i < 8; i++)
        #pragma unroll
        for (int j = 0; j < 8; j++) acc[i][j] = 0.f;

    for (int kk2 = 0; kk2 < 64; kk2 += 32) {
        #pragma unroll
        for (int it = 0; it < 4; it++) {
            const int idx = it * 256 + tid;
            const int row = idx >> 3;
            const int d4  = (idx & 7) * 4;
            const int grow = g0 + row;
            const float* src = (grow < 256) ? (qin + grow * D)
                             : (grow < 320) ? (kin + (grow - 256) * D)
                                            : (vin + (grow - 320) * D);
            const float4 xv = *(const float4*)(src + kbase + kk2 + d4);
            XsT[d4 + 0][row] = xv.x; XsT[d4 + 1][row] = xv.y;
            XsT[d4 + 2][row] = xv.z; XsT[d4 + 3][row] = xv.w;
        }
        #pragma unroll
        for (int it = 0; it < 8; it++) {
            const int idx = it * 256 + tid;
            const int s   = idx >> 10;
            const int rem = idx & 1023;
            const int dk  = rem >> 5;
            const int c4  = (rem & 31) * 4;
            *(float4*)&Ws2[s][dk][c4] =
                *(const float4*)((s ? Whi : Wlo) + (kbase + kk2 + dk) * D + col0 + c4);
        }
        __syncthreads();
        #pragma unroll
        for (int dk = 0; dk < 32; dk++) {
            const float4 xa = *(const float4*)&XsT[dk][half * 64 + r0a];
            const float4 xb = *(const float4*)&XsT[dk][half * 64 + r0a + 32];
            const float4 wa = *(const float4*)&Ws2[half][dk][c0a];
            const float4 wb = *(const float4*)&Ws2[half][dk][c0a + 64];
            const float xr[8] = {xa.x, xa.y, xa.z, xa.w, xb.x, xb.y, xb.z, xb.w};
            const float wc[8] = {wa.x, wa.y, wa.z, wa.w, wb.x, wb.y, wb.z, wb.w};
            #pragma unroll
            for (int i = 0; i < 8; i++)
                #pragma unroll
                for (int j = 0; j < 8; j++)
                    acc[i][j] = fmaf(xr[i], wc[j], acc[i][j]);
        }
        __syncthreads();
    }
    float* P = ws + OFF_PP + ks * (ROWS * D);
    #pragma unroll
    for (int i = 0; i < 8; i++) {
        const int row = g0 + half * 64 + r0a + (i < 4 ? i : 28 + i);
        *(float4*)(P + row * D + col0 + c0a) =
            make_float4(acc[i][0], acc[i][1], acc[i][2], acc[i][3]);
        *(float4*)(P + row * D + col0 + c0a + 64) =
            make_float4(acc[i][4], acc[i][5], acc[i][6], acc[i][7]);
    }
}

__global__ __launch_bounds__(256, 1) void ab_kernel(
    const float* __restrict__ memo,
    const float* __restrict__ bq_, const float* __restrict__ bk_,
    float* __restrict__ ws)
{
    const int nh = blockIdx.x;
    const int rg = blockIdx.y;
    const int n = nh >> 4, h = nh & 15;
    const float* PP = ws + OFF_PP;
    float* A = ws + OFF_A;
    float* B = ws + OFF_B;

    __shared__ float QsT[48][68];
    __shared__ float RsT[48][132];

    const int tid = threadIdx.x;
    for (int l = tid; l < 64 * 12; l += 256) {
        const int q  = l / 12;
        const int d4 = (l % 12) * 4;
        float4 s = make_float4(0.f, 0.f, 0.f, 0.f);
        #pragma unroll
        for (int c = 0; c < SPLITK; c++) {
            const float4 p = *(const float4*)(PP + c * (ROWS * D) + (n * QL + q) * D + h * HD + d4);
            s.x += p.x; s.y += p.y; s.z += p.z; s.w += p.w;
        }
        const float4 bb = *(const float4*)(bq_ + h * HD + d4);
        QsT[d4 + 0][q] = s.x + bb.x; QsT[d4 + 1][q] = s.y + bb.y;
        QsT[d4 + 2][q] = s.z + bb.z; QsT[d4 + 3][q] = s.w + bb.w;
    }
    for (int l = tid; l < 128 * 12; l += 256) {
        const int row = l / 12;
        const int d4  = (l % 12) * 4;
        const int rr  = rg * 128 + row;
        float4 s = make_float4(0.f, 0.f, 0.f, 0.f);
        if (rr < E) {
            s = *(const float4*)(memo + rr * D + h * HD + d4);
        } else if (rr < E + KL) {
            #pragma unroll
            for (int c = 0; c < SPLITK; c++) {
                const float4 p = *(const float4*)(PP + c * (ROWS * D) + (256 + rr - E) * D + h * HD + d4);
                s.x += p.x; s.y += p.y; s.z += p.z; s.w += p.w;
            }
            const float4 bb = *(const float4*)(bk_ + h * HD + d4);
            s.x += bb.x; s.y += bb.y; s.z += bb.z; s.w += bb.w;
        }
        RsT[d4 + 0][row] = s.x; RsT[d4 + 1][row] = s.y;
        RsT[d4 + 2][row] = s.z; RsT[d4 + 3][row] = s.w;
    }
    __syncthreads();

    const int r0 = (tid >> 4) * 8;
    const int q0 = (tid & 15) * 4;
    float acc[8][4];
    #pragma unroll
    for (int i = 0; i < 8; i++)
        #pragma unroll
        for (int j = 0; j < 4; j++) acc[i][j] = 0.f;

    #pragma unroll 4
    for (int d = 0; d < HD; d++) {
        const float4 rf0 = *(const float4*)&RsT[d][r0];
        const float4 rf1 = *(const float4*)&RsT[d][r0 + 4];
        const float4 qf  = *(const float4*)&QsT[d][q0];
        const float rr8[8] = {rf0.x, rf0.y, rf0.z, rf0.w, rf1.x, rf1.y, rf1.z, rf1.w};
        #pragma unroll
        for (int i = 0; i < 8; i++) {
            acc[i][0] = fmaf(rr8[i], qf.x, acc[i][0]);
            acc[i][1] = fmaf(rr8[i], qf.y, acc[i][1]);
            acc[i][2] = fmaf(rr8[i], qf.z, acc[i][2]);
            acc[i][3] = fmaf(rr8[i], qf.w, acc[i][3]);
        }
    }
    #pragma unroll
    for (int i = 0; i < 8; i++) {
        const int rr = rg * 128 + r0 + i;
        const float4 av = make_float4(acc[i][0], acc[i][1], acc[i][2], acc[i][3]);
        if (rr < E)            *(float4*)(A + (nh * E + rr) * QL + q0) = av;
        else if (rr < E + KL)  *(float4*)(B + (nh * KL + (rr - E)) * QL + q0) = av;
    }
}

__global__ __launch_bounds__(256, 1) void main_kernel(float* __restrict__ ws)
{
    const int nh = blockIdx.x;
    const int cgI = blockIdx.y;
    const int tid = threadIdx.x;
    const int lane = tid & 63;
    const int w = tid >> 6;

    __shared__ float As[75 * 64];
    __shared__ float Bs[64][68];

    const float* Ag = ws + OFF_A + (nh * E + cgI * 75) * QL;
    for (int idx = tid; idx < 1200; idx += 256)
        *(float4*)&As[idx * 4] = *(const float4*)(Ag + idx * 4);
    const float* Bg = ws + OFF_B + nh * (KL * QL);
    #pragma unroll
    for (int it = 0; it < 4; it++) {
        const int idx = it * 256 + tid;
        const int k  = idx >> 4;
        const int q4 = (idx & 15) * 4;
        *(float4*)&Bs[k][q4] = *(const float4*)(Bg + idx * 4);
    }
    __syncthreads();

    float b[64];
    #pragma unroll
    for (int j = 0; j < 16; j++)
        *(float4*)&b[j * 4] = *(const float4*)&Bs[lane][j * 4];

    float s[64];
    #pragma unroll
    for (int j = 0; j < 64; j++) s[j] = 0.f;

    const int eBeg = w * 19;
    const int eEnd = (eBeg + 19 < 75) ? eBeg + 19 : 75;
    for (int e = eBeg; e < eEnd; e++) {
        float m[64];
        #pragma unroll
        for (int j4 = 0; j4 < 16; j4++) {
            const float4 a = *(const float4*)&As[e * 64 + j4 * 4];
            m[j4 * 4 + 0] = fmaxf(a.x + b[j4 * 4 + 0], 0.f);
            m[j4 * 4 + 1] = fmaxf(a.y + b[j4 * 4 + 1], 0.f);
            m[j4 * 4 + 2] = fmaxf(a.z + b[j4 * 4 + 2], 0.f);
            m[j4 * 4 + 3] = fmaxf(a.w + b[j4 * 4 + 3], 0.f);
        }
        float p0 = 0.f, p1 = 0.f, p2 = 0.f, p3 = 0.f;
        #pragma unroll
        for (int j4 = 0; j4 < 16; j4++) {
            p0 += m[j4 * 4 + 0]; p1 += m[j4 * 4 + 1];
            p2 += m[j4 * 4 + 2]; p3 += m[j4 * 4 + 3];
        }
        const float p = (p0 + p1) + (p2 + p3);
        #pragma unroll
        for (int j = 0; j < 64; j++)
            s[j] = fmaf(m[j], p, s[j]);
    }

    float* Sp = ws + OFF_SP + ((cgI * 4 + w) * NH + nh) * (QL * KL);
    #pragma unroll
    for (int q = 0; q < 64; q++)
        Sp[q * KL + lane] = s[q];
}

__global__ __launch_bounds__(256, 1) void out_kernel(
    const float* __restrict__ ws_c, const float* __restrict__ bv_, float* __restrict__ outp)
{
    const int nh = blockIdx.x;
    const int qq = blockIdx.y;
    const int n = nh >> 4, h = nh & 15;
    const int q0 = qq * 16;
    const float* Sp = ws_c + OFF_SP;
    const float* PP = ws_c + OFF_PP;

    __shared__ float S_l[16][65];
    __shared__ float V_l[64][52];

    const int tid = threadIdx.x;
    for (int l = tid; l < 64 * 12; l += 256) {
        const int k  = l / 12;
        const int d4 = (l % 12) * 4;
        float4 s = make_float4(0.f, 0.f, 0.f, 0.f);
        #pragma unroll
        for (int c = 0; c < SPLITK; c++) {
            const float4 p = *(const float4*)(PP + c * (ROWS * D) + (320 + k) * D + h * HD + d4);
            s.x += p.x; s.y += p.y; s.z += p.z; s.w += p.w;
        }
        const float4 bb = *(const float4*)(bv_ + h * HD + d4);
        *(float4*)&V_l[k][d4] = make_float4(s.x + bb.x, s.y + bb.y, s.z + bb.z, s.w + bb.w);
    }
    #pragma unroll
    for (int it = 0; it < 4; it++) {
        const int idx = it * 256 + tid;
        const int qi = idx >> 6, k = idx & 63;
        float sum = 0.f;
        #pragma unroll
        for (int c = 0; c < NCHUNK; c++)
            sum += Sp[((c * NH + nh) * QL + q0 + qi) * KL + k];
        S_l[qi][k] = sum;
    }
    __syncthreads();

    const int qi = tid >> 4;
    const int dg = tid & 15;
    if (dg < 12) {
        float a0 = 0.f, a1 = 0.f, a2 = 0.f, a3 = 0.f;
        #pragma unroll 8
        for (int k = 0; k < KL; k++) {
            const float sv = S_l[qi][k];
            const float4 vf = *(const float4*)&V_l[k][dg * 4];
            a0 = fmaf(sv, vf.x, a0); a1 = fmaf(sv, vf.y, a1);
            a2 = fmaf(sv, vf.z, a2); a3 = fmaf(sv, vf.w, a3);
        }
        *(float4*)(outp + (n * QL + q0 + qi) * D + h * HD + dg * 4) =
            make_float4(a0, a1, a2, a3);
    }
}

// ---------------------------------------------------------------------------
extern "C" void kernel_launch(void* const* d_in, const int* in_sizes, int n_in,
                              void* d_out, int out_size, void* d_ws, size_t ws_size,
                              hipStream_t stream)
{
    const float* q    = (const float*)d_in[0];
    const float* k    = (const float*)d_in[1];
    const float* v    = (const float*)d_in[2];
    const float* Wq   = (const float*)d_in[3];
    const float* bq   = (const float*)d_in[4];
    const float* Wk   = (const float*)d_in[5];
    const float* bk   = (const float*)d_in[6];
    const float* Wv   = (const float*)d_in[7];
    const float* bv   = (const float*)d_in[8];
    const float* memo = (const float*)d_in[9];
    float* ws   = (float*)d_ws;
    float* outp = (float*)d_out;

    // zero the barrier counters (captured as a memset node; re-runs every replay
    // since the harness re-poisons d_ws to 0xAA before each timed launch)
    hipMemsetAsync((char*)d_ws + (size_t)OFF_BAR * sizeof(float), 0, 256, stream);

    void* args[] = {
        (void*)&q, (void*)&k, (void*)&v,
        (void*)&Wq, (void*)&bq, (void*)&Wk, (void*)&bk, (void*)&Wv, (void*)&bv,
        (void*)&memo, (void*)&ws, (void*)&outp
    };
    hipError_t err = hipLaunchCooperativeKernel((const void*)fused_kernel,
                                                dim3(NBLK), dim3(256), args, 0, stream);
    if (err != hipSuccess) {
        (void)hipGetLastError();   // clear sticky error, take discrete path
        hipLaunchKernelGGL(proj_kernel, dim3(3, 6, 12), dim3(256), 0, stream,
                           q, k, v, Wq, Wk, Wv, ws);
        hipLaunchKernelGGL(ab_kernel, dim3(64, 3), dim3(256), 0, stream, memo, bq, bk, ws);
        hipLaunchKernelGGL(main_kernel, dim3(64, 4), dim3(256), 0, stream, ws);
        hipLaunchKernelGGL(out_kernel, dim3(64, 4), dim3(256), 0, stream, ws, bv, outp);
    }
}

// Round 8
// 140.677 us; speedup vs baseline: 2.6164x; 2.6164x over previous
//
#include <hip/hip_runtime.h>

// Problem constants
#define H   16
#define E   300
#define D   768
#define HD  48
#define QL  64
#define KL  64
#define NH  64          // n(4) * h(16)
#define ROWS 384        // 256 Q rows + 64 K + 64 V
#define SPLITK 12
#define NCHUNK 16       // e-chunk partial count

// Workspace float offsets
#define OFF_PP 0                              // Ppart[12][384][768]
#define OFF_A  (SPLITK*ROWS*D)                // 3,538,944  A[nh][e][q]
#define OFF_B  (OFF_A + NH*E*QL)              // 4,767,744  B[nh][k][q]
#define OFF_SP (OFF_B + NH*KL*QL)             // 5,029,888  Sp[16][nh][q][k]
// end = 9,224,192 floats = 36.9 MB

// ---------------------------------------------------------------------------
// K1: QKV projection -> 12 splitK partials.  BM=128/BN=128/BK=64 per block.
// grid (3 rowblk, 6 colblk, 12 ks) = 216 blocks.  X and W staged in LDS;
// W reads use the {c0a, c0a+64} column split -> 2-way bank aliasing (free).
// Waves 0-1 = row half 0 (Wlo), waves 2-3 = half 1 (Whi).
// [Body correctness-proven inside R7's passing fused kernel.]
// ---------------------------------------------------------------------------
__global__ __launch_bounds__(256, 1) void proj_kernel(
    const float* __restrict__ qin, const float* __restrict__ kin, const float* __restrict__ vin,
    const float* __restrict__ Wq, const float* __restrict__ Wk, const float* __restrict__ Wv,
    float* __restrict__ ws)
{
    const int rowblk = blockIdx.x;
    const int col0   = blockIdx.y * 128;
    const int ks     = blockIdx.z;
    const int kbase  = ks * 64;
    const int g0     = rowblk * 128;
    const float* Wlo = (g0      < 256) ? Wq : Wk;
    const float* Whi = (g0 + 64 < 256) ? Wq : Wv;

    __shared__ float XsT[32][132];
    __shared__ float Ws2[2][32][128];

    const int tid  = threadIdx.x;
    const int half = tid >> 7;                // wave-uniform
    const int loc  = tid & 127;
    const int r0a  = (loc >> 4) * 4;          // 0..28
    const int c0a  = (loc & 15) * 4;          // 0..60

    float acc[8][8];
    #pragma unroll
    for (int i = 0; i < 8; i++)
        #pragma unroll
        for (int j = 0; j < 8; j++) acc[i][j] = 0.f;

    for (int kk2 = 0; kk2 < 64; kk2 += 32) {
        #pragma unroll
        for (int it = 0; it < 4; it++) {      // stage X tile (128 rows x 32 dk), transposed
            const int idx = it * 256 + tid;
            const int row = idx >> 3;
            const int d4  = (idx & 7) * 4;
            const int grow = g0 + row;
            const float* src = (grow < 256) ? (qin + grow * D)
                             : (grow < 320) ? (kin + (grow - 256) * D)
                                            : (vin + (grow - 320) * D);
            const float4 xv = *(const float4*)(src + kbase + kk2 + d4);
            XsT[d4 + 0][row] = xv.x; XsT[d4 + 1][row] = xv.y;
            XsT[d4 + 2][row] = xv.z; XsT[d4 + 3][row] = xv.w;
        }
        #pragma unroll
        for (int it = 0; it < 8; it++) {      // stage both W tiles (2 x 32 dk x 128 cols)
            const int idx = it * 256 + tid;
            const int s   = idx >> 10;
            const int rem = idx & 1023;
            const int dk  = rem >> 5;
            const int c4  = (rem & 31) * 4;
            *(float4*)&Ws2[s][dk][c4] =
                *(const float4*)((s ? Whi : Wlo) + (kbase + kk2 + dk) * D + col0 + c4);
        }
        __syncthreads();
        #pragma unroll
        for (int dk = 0; dk < 32; dk++) {
            const float4 xa = *(const float4*)&XsT[dk][half * 64 + r0a];
            const float4 xb = *(const float4*)&XsT[dk][half * 64 + r0a + 32];
            const float4 wa = *(const float4*)&Ws2[half][dk][c0a];
            const float4 wb = *(const float4*)&Ws2[half][dk][c0a + 64];
            const float xr[8] = {xa.x, xa.y, xa.z, xa.w, xb.x, xb.y, xb.z, xb.w};
            const float wc[8] = {wa.x, wa.y, wa.z, wa.w, wb.x, wb.y, wb.z, wb.w};
            #pragma unroll
            for (int i = 0; i < 8; i++)
                #pragma unroll
                for (int j = 0; j < 8; j++)
                    acc[i][j] = fmaf(xr[i], wc[j], acc[i][j]);
        }
        __syncthreads();
    }
    float* P = ws + OFF_PP + ks * (ROWS * D);
    #pragma unroll
    for (int i = 0; i < 8; i++) {
        const int row = g0 + half * 64 + r0a + (i < 4 ? i : 28 + i);
        *(float4*)(P + row * D + col0 + c0a) =
            make_float4(acc[i][0], acc[i][1], acc[i][2], acc[i][3]);
        *(float4*)(P + row * D + col0 + c0a + 64) =
            make_float4(acc[i][4], acc[i][5], acc[i][6], acc[i][7]);
    }
}

// ---------------------------------------------------------------------------
// K2: A[nh][e][q] = mem_e.Q_q ; B[nh][k][q] = K_k.Q_q.
// 12-partial reduce + bias folded into Q/K LDS staging (no separate reduce
// dispatch).  Transposed tiles, 8x4 microtile.  grid (64 nh, 3 rowgroups).
// ---------------------------------------------------------------------------
__global__ __launch_bounds__(256, 1) void ab_kernel(
    const float* __restrict__ memo,
    const float* __restrict__ bq_, const float* __restrict__ bk_,
    float* __restrict__ ws)
{
    const int nh = blockIdx.x;
    const int rg = blockIdx.y;                // 0..2
    const int n = nh >> 4, h = nh & 15;
    const float* PP = ws + OFF_PP;
    float* A = ws + OFF_A;
    float* B = ws + OFF_B;

    __shared__ float QsT[48][68];
    __shared__ float RsT[48][132];

    const int tid = threadIdx.x;
    for (int l = tid; l < 64 * 12; l += 256) {   // Q: reduce 12 + bias, transposed
        const int q  = l / 12;
        const int d4 = (l % 12) * 4;
        float4 s = make_float4(0.f, 0.f, 0.f, 0.f);
        #pragma unroll
        for (int c = 0; c < SPLITK; c++) {
            const float4 p = *(const float4*)(PP + c * (ROWS * D) + (n * QL + q) * D + h * HD + d4);
            s.x += p.x; s.y += p.y; s.z += p.z; s.w += p.w;
        }
        const float4 bb = *(const float4*)(bq_ + h * HD + d4);
        QsT[d4 + 0][q] = s.x + bb.x; QsT[d4 + 1][q] = s.y + bb.y;
        QsT[d4 + 2][q] = s.z + bb.z; QsT[d4 + 3][q] = s.w + bb.w;
    }
    for (int l = tid; l < 128 * 12; l += 256) {  // rows: memo or K(reduce+bias)
        const int row = l / 12;
        const int d4  = (l % 12) * 4;
        const int rr  = rg * 128 + row;
        float4 s = make_float4(0.f, 0.f, 0.f, 0.f);
        if (rr < E) {
            s = *(const float4*)(memo + rr * D + h * HD + d4);
        } else if (rr < E + KL) {
            #pragma unroll
            for (int c = 0; c < SPLITK; c++) {
                const float4 p = *(const float4*)(PP + c * (ROWS * D) + (256 + rr - E) * D + h * HD + d4);
                s.x += p.x; s.y += p.y; s.z += p.z; s.w += p.w;
            }
            const float4 bb = *(const float4*)(bk_ + h * HD + d4);
            s.x += bb.x; s.y += bb.y; s.z += bb.z; s.w += bb.w;
        }
        RsT[d4 + 0][row] = s.x; RsT[d4 + 1][row] = s.y;
        RsT[d4 + 2][row] = s.z; RsT[d4 + 3][row] = s.w;
    }
    __syncthreads();

    const int r0 = (tid >> 4) * 8;            // 0..120
    const int q0 = (tid & 15) * 4;            // 0..60
    float acc[8][4];
    #pragma unroll
    for (int i = 0; i < 8; i++)
        #pragma unroll
        for (int j = 0; j < 4; j++) acc[i][j] = 0.f;

    #pragma unroll 4
    for (int d = 0; d < HD; d++) {
        const float4 rf0 = *(const float4*)&RsT[d][r0];
        const float4 rf1 = *(const float4*)&RsT[d][r0 + 4];
        const float4 qf  = *(const float4*)&QsT[d][q0];
        const float rr8[8] = {rf0.x, rf0.y, rf0.z, rf0.w, rf1.x, rf1.y, rf1.z, rf1.w};
        #pragma unroll
        for (int i = 0; i < 8; i++) {
            acc[i][0] = fmaf(rr8[i], qf.x, acc[i][0]);
            acc[i][1] = fmaf(rr8[i], qf.y, acc[i][1]);
            acc[i][2] = fmaf(rr8[i], qf.z, acc[i][2]);
            acc[i][3] = fmaf(rr8[i], qf.w, acc[i][3]);
        }
    }
    #pragma unroll
    for (int i = 0; i < 8; i++) {
        const int rr = rg * 128 + r0 + i;
        const float4 av = make_float4(acc[i][0], acc[i][1], acc[i][2], acc[i][3]);
        if (rr < E)            *(float4*)(A + (nh * E + rr) * QL + q0) = av;
        else if (rr < E + KL)  *(float4*)(B + (nh * KL + (rr - E)) * QL + q0) = av;
    }
}

// ---------------------------------------------------------------------------
// K3: fused core.  Block (nh, cg); wave w -> 19-e chunk of this cg's 75 e.
// lane = k; all 64 q in registers.  A rows broadcast from LDS (b128, same
// address across lanes).  m=relu(A+b); p=sum_q m; s+=m*p.  Sp partial/chunk.
// grid (64, 4) = 256 blocks.
// ---------------------------------------------------------------------------
__global__ __launch_bounds__(256, 1) void main_kernel(float* __restrict__ ws)
{
    const int nh = blockIdx.x;
    const int cgI = blockIdx.y;               // 0..3
    const int tid = threadIdx.x;
    const int lane = tid & 63;                // k
    const int w = tid >> 6;                   // 0..3

    __shared__ float As[75 * 64];
    __shared__ float Bs[64][68];

    const float* Ag = ws + OFF_A + (nh * E + cgI * 75) * QL;
    for (int idx = tid; idx < 1200; idx += 256)
        *(float4*)&As[idx * 4] = *(const float4*)(Ag + idx * 4);
    const float* Bg = ws + OFF_B + nh * (KL * QL);
    #pragma unroll
    for (int it = 0; it < 4; it++) {
        const int idx = it * 256 + tid;
        const int k  = idx >> 4;
        const int q4 = (idx & 15) * 4;
        *(float4*)&Bs[k][q4] = *(const float4*)(Bg + idx * 4);
    }
    __syncthreads();

    float b[64];
    #pragma unroll
    for (int j = 0; j < 16; j++)
        *(float4*)&b[j * 4] = *(const float4*)&Bs[lane][j * 4];

    float s[64];
    #pragma unroll
    for (int j = 0; j < 64; j++) s[j] = 0.f;

    const int eBeg = w * 19;
    const int eEnd = (eBeg + 19 < 75) ? eBeg + 19 : 75;
    for (int e = eBeg; e < eEnd; e++) {
        float m[64];
        #pragma unroll
        for (int j4 = 0; j4 < 16; j4++) {
            const float4 a = *(const float4*)&As[e * 64 + j4 * 4];  // broadcast
            m[j4 * 4 + 0] = fmaxf(a.x + b[j4 * 4 + 0], 0.f);
            m[j4 * 4 + 1] = fmaxf(a.y + b[j4 * 4 + 1], 0.f);
            m[j4 * 4 + 2] = fmaxf(a.z + b[j4 * 4 + 2], 0.f);
            m[j4 * 4 + 3] = fmaxf(a.w + b[j4 * 4 + 3], 0.f);
        }
        float p0 = 0.f, p1 = 0.f, p2 = 0.f, p3 = 0.f;
        #pragma unroll
        for (int j4 = 0; j4 < 16; j4++) {
            p0 += m[j4 * 4 + 0]; p1 += m[j4 * 4 + 1];
            p2 += m[j4 * 4 + 2]; p3 += m[j4 * 4 + 3];
        }
        const float p = (p0 + p1) + (p2 + p3);
        #pragma unroll
        for (int j = 0; j < 64; j++)
            s[j] = fmaf(m[j], p, s[j]);
    }

    float* Sp = ws + OFF_SP + ((cgI * 4 + w) * NH + nh) * (QL * KL);
    #pragma unroll
    for (int q = 0; q < 64; q++)
        Sp[q * KL + lane] = s[q];
}

// ---------------------------------------------------------------------------
// K4: S = sum of 16 partials;  out[n,q,h,d] = sum_k S[q,k] * V[k,h,d].
// V reduced from 12 proj partials + bias in-kernel.  S_l padded to 65
// (stride-64 would be a 16-way conflict).  grid (64 nh, 4 q-quarters).
// ---------------------------------------------------------------------------
__global__ __launch_bounds__(256, 1) void out_kernel(
    const float* __restrict__ ws_c, const float* __restrict__ bv_, float* __restrict__ outp)
{
    const int nh = blockIdx.x;
    const int qq = blockIdx.y;
    const int n = nh >> 4, h = nh & 15;
    const int q0 = qq * 16;
    const float* Sp = ws_c + OFF_SP;
    const float* PP = ws_c + OFF_PP;

    __shared__ float S_l[16][65];
    __shared__ float V_l[64][52];

    const int tid = threadIdx.x;
    for (int l = tid; l < 64 * 12; l += 256) {   // V: reduce 12 + bias
        const int k  = l / 12;
        const int d4 = (l % 12) * 4;
        float4 s = make_float4(0.f, 0.f, 0.f, 0.f);
        #pragma unroll
        for (int c = 0; c < SPLITK; c++) {
            const float4 p = *(const float4*)(PP + c * (ROWS * D) + (320 + k) * D + h * HD + d4);
            s.x += p.x; s.y += p.y; s.z += p.z; s.w += p.w;
        }
        const float4 bb = *(const float4*)(bv_ + h * HD + d4);
        *(float4*)&V_l[k][d4] = make_float4(s.x + bb.x, s.y + bb.y, s.z + bb.z, s.w + bb.w);
    }
    #pragma unroll
    for (int it = 0; it < 4; it++) {             // sum 16 S-partials
        const int idx = it * 256 + tid;
        const int qi = idx >> 6, k = idx & 63;
        float sum = 0.f;
        #pragma unroll
        for (int c = 0; c < NCHUNK; c++)
            sum += Sp[((c * NH + nh) * QL + q0 + qi) * KL + k];
        S_l[qi][k] = sum;
    }
    __syncthreads();

    const int qi = tid >> 4;                     // 0..15
    const int dg = tid & 15;                     // 12 active
    if (dg < 12) {
        float a0 = 0.f, a1 = 0.f, a2 = 0.f, a3 = 0.f;
        #pragma unroll 8
        for (int k = 0; k < KL; k++) {
            const float sv = S_l[qi][k];
            const float4 vf = *(const float4*)&V_l[k][dg * 4];
            a0 = fmaf(sv, vf.x, a0); a1 = fmaf(sv, vf.y, a1);
            a2 = fmaf(sv, vf.z, a2); a3 = fmaf(sv, vf.w, a3);
        }
        *(float4*)(outp + (n * QL + q0 + qi) * D + h * HD + dg * 4) =
            make_float4(a0, a1, a2, a3);
    }
}

// ---------------------------------------------------------------------------
extern "C" void kernel_launch(void* const* d_in, const int* in_sizes, int n_in,
                              void* d_out, int out_size, void* d_ws, size_t ws_size,
                              hipStream_t stream)
{
    const float* q    = (const float*)d_in[0];
    const float* k    = (const float*)d_in[1];
    const float* v    = (const float*)d_in[2];
    const float* Wq   = (const float*)d_in[3];
    const float* bq   = (const float*)d_in[4];
    const float* Wk   = (const float*)d_in[5];
    const float* bk   = (const float*)d_in[6];
    const float* Wv   = (const float*)d_in[7];
    const float* bv   = (const float*)d_in[8];
    const float* memo = (const float*)d_in[9];
    float* ws   = (float*)d_ws;
    float* outp = (float*)d_out;

    hipLaunchKernelGGL(proj_kernel, dim3(3, 6, 12), dim3(256), 0, stream,
                       q, k, v, Wq, Wk, Wv, ws);
    hipLaunchKernelGGL(ab_kernel, dim3(64, 3), dim3(256), 0, stream, memo, bq, bk, ws);
    hipLaunchKernelGGL(main_kernel, dim3(64, 4), dim3(256), 0, stream, ws);
    hipLaunchKernelGGL(out_kernel, dim3(64, 4), dim3(256), 0, stream, ws, bv, outp);
}